// Round 11
// baseline (2787.863 us; speedup 1.0000x reference)
//
#include <hip/hip_runtime.h>
#include <stdint.h>

#define BATCH 512
#define TMAX 1024
#define DIN 4
#define H 64
#define NC 1098
#define GQ 16   // sequences per block (MFMA N-tile); lengths sorted desc

typedef _Float16 f16;
typedef _Float16 f16x8 __attribute__((ext_vector_type(8)));
typedef float f32x4 __attribute__((ext_vector_type(4)));

#define MFMA16(a, b, c) __builtin_amdgcn_mfma_f32_16x16x32_f16((a), (b), (c), 0, 0, 0)
// LDS-only barrier (no vmcnt drain): flush stores / prefetch loads stay in
// flight across steps. "memory" clobber = compiler fence.
#define RAW_BARRIER() asm volatile("s_waitcnt lgkmcnt(0)\n\ts_barrier" ::: "memory")

__device__ __forceinline__ float sigmoidf_(float x) {
    return 1.0f / (1.0f + __expf(-x));
}
__device__ __forceinline__ float tanhf_(float x) {
    return 1.0f - 2.0f / (__expf(2.0f * x) + 1.0f);
}
__device__ __forceinline__ f16x8 cvt8(float4 a, float4 b) {
    f16x8 r;
    r[0]=(f16)a.x; r[1]=(f16)a.y; r[2]=(f16)a.z; r[3]=(f16)a.w;
    r[4]=(f16)b.x; r[5]=(f16)b.y; r[6]=(f16)b.z; r[7]=(f16)b.w;
    return r;
}
__device__ __forceinline__ f16x8 zero8() {
    f16x8 r;
    #pragma unroll
    for (int z = 0; z < 8; z++) r[z] = (f16)0.f;
    return r;
}

// 16 waves / block, ONE 16x16 M-tile per wave (R10 had 4 tiles/wave on 4
// waves -> 16 gate-activations/lane/step of critical-path transcendentals).
// Row interleave R = 4j + gate (source weight row sr=(R&3)*64+(R>>2)):
//   A-frag lane(q,n): rows R=16w+n, k=q*8+idx
//   C/D lane(q,n): regs = gates (i,f,g,o) of h-index j=4w+q, seq n
// -> ONE c/h update + ~5 transcendentals per lane per step.

// ================= Layer 0: K = 64(h) + 4(x), 3 MFMA / wave / step ==========
__global__ __launch_bounds__(1024) void lstm0_mfma(
    const float* __restrict__ x, const int* __restrict__ lengths,
    const float* __restrict__ Wih_f, const float* __restrict__ Whh_f,
    const float* __restrict__ bih_f, const float* __restrict__ bhh_f,
    const float* __restrict__ Wih_b, const float* __restrict__ Whh_b,
    const float* __restrict__ bih_b, const float* __restrict__ bhh_b,
    f16* __restrict__ h0b /* [B, T, 2H] f16 */)
{
    const int g = blockIdx.x, dir = blockIdx.y;
    const int tid = threadIdx.x;
    const int lane = tid & 63, w = tid >> 6;       // w in 0..15 = M-tile
    const int q = lane >> 4, n = lane & 15;
    const int seq0 = g * GQ;

    const float* Wih = dir ? Wih_b : Wih_f;
    const float* Whh = dir ? Whh_b : Whh_f;
    const float* bih = dir ? bih_b : bih_f;
    const float* bhh = dir ? bhh_b : bhh_f;

    __shared__ int Ls[GQ];
    __shared__ __align__(16) f16 ring[16][GQ][72]; // unified h ring (36 KB)

    if (tid < GQ) Ls[tid] = lengths[seq0 + tid];
    if (tid < GQ * 8)                              // zero slot 15 (h(-1)=0)
        *(f16x8*)&ring[15][tid >> 3][(tid & 7) * 8] = zero8();
    __syncthreads();
    int maxL = 0;
    #pragma unroll
    for (int i2 = 0; i2 < GQ; i2++) maxL = max(maxL, Ls[i2]);
    const int Ln = Ls[n];

    // A-frags for this wave's tile (rows R = 16w + n)
    const int R = 16 * w + n;
    const int sr = (R & 3) * H + (R >> 2);
    f16x8 ahh0, ahh1, afx;
    {
        const float4* ph = (const float4*)(Whh + (size_t)sr * H);
        ahh0 = cvt8(ph[2*q],     ph[2*q + 1]);
        ahh1 = cvt8(ph[8 + 2*q], ph[8 + 2*q + 1]);
        f16x8 a2 = zero8();
        if (q == 0) {
            const float4 wv = *(const float4*)(Wih + (size_t)sr * DIN);
            a2[0]=(f16)wv.x; a2[1]=(f16)wv.y; a2[2]=(f16)wv.z; a2[3]=(f16)wv.w;
        }
        afx = a2;
    }
    const int j = 4 * w + q;                        // this lane's h-index
    f32x4 bias4;
    bias4.x = bih[j]       + bhh[j];
    bias4.y = bih[H + j]   + bhh[H + j];
    bias4.z = bih[2*H + j] + bhh[2*H + j];
    bias4.w = bih[3*H + j] + bhh[3*H + j];

    auto xload = [&](int s) -> float4 {             // only q==0 lanes use it
        int tt = dir ? (Ln - 1 - s) : s;
        tt = min(max(tt, 0), TMAX - 1);
        return *(const float4*)(x + ((size_t)(seq0 + n) * TMAX + tt) * DIN);
    };
    auto flushf = [&](int first, int cnt) {         // h0 stores, NEVER drained
        for (int i = tid; i < cnt * GQ * 8; i += 1024) {
            const int k8 = i & 7, sq = (i >> 3) & 15, sl = i >> 7;
            const int ss = first + sl;
            if (ss < Ls[sq]) {
                const int t2 = dir ? (Ls[sq] - 1 - ss) : ss;
                f16x8 v = *(const f16x8*)&ring[ss & 15][sq][k8 * 8];
                *(f16x8*)(h0b + ((size_t)(seq0 + sq) * TMAX + t2) * (2*H)
                          + dir * H + k8 * 8) = v;
            }
        }
    };

    float4 xr0 = make_float4(0,0,0,0), xr1 = make_float4(0,0,0,0);
    if (q == 0) { xr0 = xload(0); xr1 = xload(1); }
    float cst = 0.0f;

    for (int s = 0; s < maxL; s++) {
        const int ps = (s + 15) & 15;               // slot holding h(s-1)
        f16x8 hb0 = *(const f16x8*)&ring[ps][n][q*8];
        f16x8 hb1 = *(const f16x8*)&ring[ps][n][32 + q*8];
        if ((s & 7) == 0 && s > 0) flushf(s - 8, 8);

        f16x8 xb = zero8();
        if (q == 0) { xb[0]=(f16)xr0.x; xb[1]=(f16)xr0.y; xb[2]=(f16)xr0.z; xb[3]=(f16)xr0.w; }

        f32x4 a = MFMA16(afx, xb, bias4);           // issues before hb lands
        a = MFMA16(ahh0, hb0, a);
        a = MFMA16(ahh1, hb1, a);

        xr0 = xr1;
        if (q == 0 && s + 2 < maxL) xr1 = xload(s + 2);

        // ONE gate quadruple per lane: regs = (i, f, g, o) of (j, seq n)
        const float gi = sigmoidf_(a.x);
        const float gf = sigmoidf_(a.y);
        const float gg = tanhf_(a.z);
        const float go = sigmoidf_(a.w);
        cst = fmaf(gf, cst, gi * gg);
        ring[s & 15][n][j] = (f16)(go * tanhf_(cst));
        RAW_BARRIER();
    }
    const int fstart = (maxL - 1) & ~7;             // tail rows
    flushf(fstart, maxL - fstart);
}

// ===== Layer 1 fwd: K = 64(h) + 128(h0 row), 6 MFMA / wave / step ===========
__global__ __launch_bounds__(1024) void lstm1_mfma(
    const f16* __restrict__ h0b, const int* __restrict__ lengths,
    const float* __restrict__ Wih, const float* __restrict__ Whh,
    const float* __restrict__ bih, const float* __restrict__ bhh,
    float* __restrict__ ylast /* [B, H] fp32 */)
{
    const int g = blockIdx.x;
    const int tid = threadIdx.x;
    const int lane = tid & 63, w = tid >> 6;
    const int q = lane >> 4, n = lane & 15;
    const int seq0 = g * GQ;

    __shared__ int Ls[GQ];
    __shared__ __align__(16) f16 hx[2][GQ][72];     // parity h exchange

    if (tid < GQ) Ls[tid] = lengths[seq0 + tid];
    if (tid < GQ * 8)                               // zero slot 1 (h(-1)=0)
        *(f16x8*)&hx[1][tid >> 3][(tid & 7) * 8] = zero8();
    __syncthreads();
    int maxL = 0;
    #pragma unroll
    for (int i2 = 0; i2 < GQ; i2++) maxL = max(maxL, Ls[i2]);
    const int Lme = Ls[n];

    const int R = 16 * w + n;
    const int sr = (R & 3) * H + (R >> 2);
    f16x8 ahh0, ahh1, axw[4];
    {
        const float4* ph = (const float4*)(Whh + (size_t)sr * H);
        ahh0 = cvt8(ph[2*q],     ph[2*q + 1]);
        ahh1 = cvt8(ph[8 + 2*q], ph[8 + 2*q + 1]);
        const float4* pxw = (const float4*)(Wih + (size_t)sr * (2*H));
        #pragma unroll
        for (int f = 0; f < 4; f++)
            axw[f] = cvt8(pxw[f*8 + 2*q], pxw[f*8 + 2*q + 1]);
    }
    const int j = 4 * w + q;
    f32x4 bias4;
    bias4.x = bih[j]       + bhh[j];
    bias4.y = bih[H + j]   + bhh[H + j];
    bias4.z = bih[2*H + j] + bhh[2*H + j];
    bias4.w = bih[3*H + j] + bhh[3*H + j];

    auto hload = [&](int r, f16x8* dst) {           // per-lane h0-row granules
        const int rr = min(r, TMAX - 1);
        const f16* p = h0b + ((size_t)(seq0 + n) * TMAX + rr) * (2*H) + q * 8;
        #pragma unroll
        for (int f = 0; f < 4; f++) dst[f] = *(const f16x8*)(p + f * 32);
    };

    f16x8 xcur[4], xnxt[4];
    hload(0, xcur); hload(1, xnxt);                 // 2-step lookahead

    float cst = 0.0f, hlast = 0.0f;

    for (int s = 0; s < maxL; s++) {
        const int pp = (s + 1) & 1;                 // slot holding h(s-1)
        f16x8 hb0 = *(const f16x8*)&hx[pp][n][q*8];
        f16x8 hb1 = *(const f16x8*)&hx[pp][n][32 + q*8];

        f32x4 a = bias4;                            // xW issues in ds_read
        a = MFMA16(axw[0], xcur[0], a);             // latency shadow
        a = MFMA16(axw[1], xcur[1], a);
        a = MFMA16(axw[2], xcur[2], a);
        a = MFMA16(axw[3], xcur[3], a);
        a = MFMA16(ahh0, hb0, a);                   // serial part
        a = MFMA16(ahh1, hb1, a);

        #pragma unroll
        for (int f = 0; f < 4; f++) xcur[f] = xnxt[f];
        if (s + 2 < maxL) hload(s + 2, xnxt);

        const float gi = sigmoidf_(a.x);
        const float gf = sigmoidf_(a.y);
        const float gg = tanhf_(a.z);
        const float go = sigmoidf_(a.w);
        cst = fmaf(gf, cst, gi * gg);
        const float h = go * tanhf_(cst);
        if (s == Lme - 1) hlast = h;                // per-lane (seq n) snap
        hx[s & 1][n][j] = (f16)h;
        RAW_BARRIER();
    }
    ylast[(size_t)(seq0 + n) * H + j] = hlast;
}

// ====== Epilogue: bwd first step (zero state -> Whh_l1b unused) + logits ====
__global__ __launch_bounds__(256) void epi_kernel(
    const f16* __restrict__ h0b, const float* __restrict__ ylast,
    const int* __restrict__ lengths,
    const float* __restrict__ Wih_b,
    const float* __restrict__ bih_b, const float* __restrict__ bhh_b,
    const float* __restrict__ Wout, const float* __restrict__ bout,
    float* __restrict__ out)
{
    const int b = blockIdx.x;
    const int t = threadIdx.x;
    const int L = lengths[b];
    __shared__ __align__(16) float y[2*H];
    __shared__ __align__(16) float xrow[2*H];
    __shared__ float gb[256];

    if (t < 2*H) xrow[t] = (float)h0b[((size_t)b * TMAX + (L - 1)) * (2*H) + t];
    if (t < H)   y[t] = ylast[(size_t)b * H + t];
    __syncthreads();
    {
        float a0 = bih_b[t] + bhh_b[t], a1 = 0.f, a2 = 0.f, a3 = 0.f;
        const float4* wr = (const float4*)(Wih_b + (size_t)t * (2*H));
        const float4* xv = (const float4*)xrow;
        #pragma unroll
        for (int k = 0; k < 32; k++) {
            float4 wv = wr[k], xk = xv[k];
            a0 = fmaf(wv.x, xk.x, a0); a1 = fmaf(wv.y, xk.y, a1);
            a2 = fmaf(wv.z, xk.z, a2); a3 = fmaf(wv.w, xk.w, a3);
        }
        const float a = (a0 + a1) + (a2 + a3);
        gb[t] = (t >= 128 && t < 192) ? tanhf_(a) : sigmoidf_(a);
    }
    __syncthreads();
    if (t < H) {
        const float cb = gb[t] * gb[128 + t];       // c_prev = 0, f unused
        y[H + t] = gb[192 + t] * tanhf_(cb);
    }
    __syncthreads();

    const float4* yv = (const float4*)y;
    for (int o = t; o < NC; o += 256) {
        float a0 = bout[o], a1 = 0.f, a2 = 0.f, a3 = 0.f;
        const float4* wr = (const float4*)(Wout + (size_t)o * (2*H));
        #pragma unroll
        for (int k = 0; k < 32; k++) {
            float4 wv = wr[k], yy = yv[k];
            a0 = fmaf(wv.x, yy.x, a0); a1 = fmaf(wv.y, yy.y, a1);
            a2 = fmaf(wv.z, yy.z, a2); a3 = fmaf(wv.w, yy.w, a3);
        }
        out[(size_t)b * NC + o] = (a0 + a1) + (a2 + a3);
    }
}

extern "C" void kernel_launch(void* const* d_in, const int* in_sizes, int n_in,
                              void* d_out, int out_size, void* d_ws, size_t ws_size,
                              hipStream_t stream) {
    const float* x        = (const float*)d_in[0];
    const int*   lengths  = (const int*)  d_in[1];
    const float* Wih_l0f  = (const float*)d_in[2];
    const float* Whh_l0f  = (const float*)d_in[3];
    const float* bih_l0f  = (const float*)d_in[4];
    const float* bhh_l0f  = (const float*)d_in[5];
    const float* Wih_l0b  = (const float*)d_in[6];
    const float* Whh_l0b  = (const float*)d_in[7];
    const float* bih_l0b  = (const float*)d_in[8];
    const float* bhh_l0b  = (const float*)d_in[9];
    const float* Wih_l1f  = (const float*)d_in[10];
    const float* Whh_l1f  = (const float*)d_in[11];
    const float* bih_l1f  = (const float*)d_in[12];
    const float* bhh_l1f  = (const float*)d_in[13];
    const float* Wih_l1b  = (const float*)d_in[14];
    // d_in[15] = Whh_l1b: unused (backward dir only needs its first step, h=0)
    const float* bih_l1b  = (const float*)d_in[16];
    const float* bhh_l1b  = (const float*)d_in[17];
    const float* Wout     = (const float*)d_in[18];
    const float* bout     = (const float*)d_in[19];
    float* out = (float*)d_out;

    // ws: h0 f16 [B,T,2H] = 128 MiB ; ylast fp32 [B,H] = 128 KiB
    f16*   h0b   = (f16*)d_ws;
    float* ylast = (float*)((char*)d_ws + (size_t)BATCH * TMAX * (2*H) * sizeof(f16));

    lstm0_mfma<<<dim3(BATCH / GQ, 2), 1024, 0, stream>>>(
        x, lengths,
        Wih_l0f, Whh_l0f, bih_l0f, bhh_l0f,
        Wih_l0b, Whh_l0b, bih_l0b, bhh_l0b, h0b);

    lstm1_mfma<<<dim3(BATCH / GQ), 1024, 0, stream>>>(
        h0b, lengths, Wih_l1f, Whh_l1f, bih_l1f, bhh_l1f, ylast);

    epi_kernel<<<dim3(BATCH), 256, 0, stream>>>(
        h0b, ylast, lengths,
        Wih_l1b, bih_l1b, bhh_l1b, Wout, bout, out);
}

// Round 12
// 1597.469 us; speedup vs baseline: 1.7452x; 1.7452x over previous
//
#include <hip/hip_runtime.h>
#include <stdint.h>

#define BATCH 512
#define TMAX 1024
#define DIN 4
#define H 64
#define NC 1098
#define CH 256   // layer-1 chunk rows; G chunk f16 = 512*256*256*2B = 64 MiB

typedef _Float16 f16;
typedef __attribute__((ext_vector_type(2))) _Float16 h2;
typedef __attribute__((ext_vector_type(4))) _Float16 f16x4;
typedef __attribute__((ext_vector_type(8))) _Float16 f16x8;
typedef __attribute__((ext_vector_type(4))) float f32x4;

#define MFMA16(a, b, c) __builtin_amdgcn_mfma_f32_16x16x32_f16((a), (b), (c), 0, 0, 0)

__device__ __forceinline__ float sigmoidf_(float x) {
    return 1.0f / (1.0f + __expf(-x));
}
__device__ __forceinline__ float tanhf_(float x) {
    return 1.0f - 2.0f / (__expf(2.0f * x) + 1.0f);
}
// f16 pair dot with fp32 accumulate: v_dot2_f32_f16 (2 MAC / instr)
__device__ __forceinline__ float dot2(h2 a, h2 b, float c) {
#if __has_builtin(__builtin_amdgcn_fdot2)
    return __builtin_amdgcn_fdot2(a, b, c, false);
#else
    return fmaf((float)a[0], (float)b[0], fmaf((float)a[1], (float)b[1], c));
#endif
}
__device__ __forceinline__ h2 hpair(f16x8 v, int i) {
    h2 r; r[0] = v[2*i]; r[1] = v[2*i + 1]; return r;
}

// ======== Layer 0: ONE WAVE per (seq,dir). ZERO barriers, zero cross-wave ===
// Lane j owns h-index j and ALL 4 gate rows {j,64+j,128+j,192+j} as f16 pairs
// (256 f16 = 128 VGPR -- the f32 version of this spilled at 256 VGPR in R3).
// Matvec = 128 v_dot2_f32_f16 over 4 independent acc chains. h round-trips
// through 128 B of LDS: same-wave ds_write -> ds_read is in-order (lgkmcnt),
// NO barrier -- R9-R11 showed the barrier rendezvous is the serial floor.
// h0 store is 2B/lane/step fire-and-forget (no barrier => never drained).
__global__ __launch_bounds__(64) void lstm0_sw(
    const float* __restrict__ x, const int* __restrict__ lengths,
    const float* __restrict__ Wih_f, const float* __restrict__ Whh_f,
    const float* __restrict__ bih_f, const float* __restrict__ bhh_f,
    const float* __restrict__ Wih_b, const float* __restrict__ Whh_b,
    const float* __restrict__ bih_b, const float* __restrict__ bhh_b,
    f16* __restrict__ h0b /* [B, T, 2H] f16 */)
{
    const int unit = blockIdx.x, b = unit >> 1, dir = unit & 1;
    const int j = threadIdx.x;
    const int L = lengths[b];

    const float* Wih = dir ? Wih_b : Wih_f;
    const float* Whh = dir ? Whh_b : Whh_f;
    const float* bih = dir ? bih_b : bih_f;
    const float* bhh = dir ? bhh_b : bhh_f;

    h2 whh2[4][32];        // 128 VGPR: rows (i,f,g,o) of h-index j, f16 pairs
    float4 wx[4];
    float bs[4];
    #pragma unroll
    for (int r = 0; r < 4; r++) {
        const float4* p = (const float4*)(Whh + (size_t)(r*H + j) * H);
        #pragma unroll
        for (int k = 0; k < 16; k++) {
            float4 v = p[k];
            h2 lo; lo[0] = (f16)v.x; lo[1] = (f16)v.y;
            h2 hi; hi[0] = (f16)v.z; hi[1] = (f16)v.w;
            whh2[r][2*k] = lo; whh2[r][2*k + 1] = hi;
        }
        wx[r] = ((const float4*)Wih)[r*H + j];
        bs[r] = bih[r*H + j] + bhh[r*H + j];
    }
    __shared__ __align__(16) f16 hbuf[H];   // 128 B
    hbuf[j] = (f16)0.f;
    float c = 0.f, h = 0.f;

    auto xld = [&](int s) -> float4 {       // broadcast (same addr all lanes)
        int tt = dir ? (L - 1 - s) : s;
        tt = min(max(tt, 0), TMAX - 1);
        return *(const float4*)(x + ((size_t)b * TMAX + tt) * DIN);
    };
    float4 x0 = xld(0), x1 = xld(1);        // 2-step register lookahead
    f16* ob = h0b + (size_t)b * TMAX * (2*H) + dir * H + j;

    for (int s = 0; s < L; s++) {
        const int t = dir ? (L - 1 - s) : s;
        f16x8 hr[8];                        // 8 broadcast ds_read_b128
        const f16x8* hp = (const f16x8*)hbuf;
        #pragma unroll
        for (int k = 0; k < 8; k++) hr[k] = hp[k];

        float a0 = bs[0], a1 = bs[1], a2 = bs[2], a3 = bs[3];
        a0 = fmaf(wx[0].x, x0.x, a0); a0 = fmaf(wx[0].y, x0.y, a0);
        a0 = fmaf(wx[0].z, x0.z, a0); a0 = fmaf(wx[0].w, x0.w, a0);
        a1 = fmaf(wx[1].x, x0.x, a1); a1 = fmaf(wx[1].y, x0.y, a1);
        a1 = fmaf(wx[1].z, x0.z, a1); a1 = fmaf(wx[1].w, x0.w, a1);
        a2 = fmaf(wx[2].x, x0.x, a2); a2 = fmaf(wx[2].y, x0.y, a2);
        a2 = fmaf(wx[2].z, x0.z, a2); a2 = fmaf(wx[2].w, x0.w, a2);
        a3 = fmaf(wx[3].x, x0.x, a3); a3 = fmaf(wx[3].y, x0.y, a3);
        a3 = fmaf(wx[3].z, x0.z, a3); a3 = fmaf(wx[3].w, x0.w, a3);
        #pragma unroll
        for (int k = 0; k < 8; k++) {
            #pragma unroll
            for (int i = 0; i < 4; i++) {
                const h2 hh = hpair(hr[k], i);
                const int p = 4*k + i;
                a0 = dot2(whh2[0][p], hh, a0);
                a1 = dot2(whh2[1][p], hh, a1);
                a2 = dot2(whh2[2][p], hh, a2);
                a3 = dot2(whh2[3][p], hh, a3);
            }
        }
        const float gi = sigmoidf_(a0), gf = sigmoidf_(a1);
        const float gg = tanhf_(a2),  go = sigmoidf_(a3);
        c = fmaf(gf, c, gi * gg);
        h = go * tanhf_(c);
        const f16 hf = (f16)h;
        hbuf[j] = hf;                       // same-wave, in-order vs next read
        ob[(size_t)t * (2*H)] = hf;         // fire-and-forget
        x0 = x1; x1 = xld(s + 2);
    }
}

// ===== prep: Wih_l1f -> gate-interleaved f16 (row R=4j+gate <- gate*64+j) ===
__global__ __launch_bounds__(256) void prep_w(
    const float* __restrict__ Wih, f16* __restrict__ Wi)
{
    const int i = blockIdx.x * 256 + threadIdx.x;   // 256*128 elems
    const int R = i >> 7, k = i & 127;
    Wi[i] = (f16)Wih[(size_t)((R & 3) * H + (R >> 2)) * (2*H) + k];
}

// ======== Layer 1 xW GEMM (MFMA, chunked): G = h0[s0:s0+CH] @ Wi^T =========
// Block = 1 seq chunk (4 waves x 64 rows). Wave w: B-frags = its 64 h0 rows
// (register-resident, reused across all 16 M-tiles); A-frags streamed from
// the 64 KB interleaved Wi (L2-resident). 64 MFMA / wave. Fully parallel --
// fixes R5's GEMM (VGPR 236 -> ~100, occupancy restored). Bias added in rec.
__global__ __launch_bounds__(256) void xw_gemm(
    const f16* __restrict__ h0b, const f16* __restrict__ Wi,
    const int* __restrict__ lengths, f16* __restrict__ G, int s0)
{
    const int b = blockIdx.x;
    const int L = lengths[b];
    const int tid = threadIdx.x, lane = tid & 63, w = tid >> 6;
    const int q = lane >> 4, n = lane & 15;
    if (s0 + w * 64 >= L) return;           // wave-uniform early out

    f16x8 bfr[4][4];                        // 4 N-tiles x 4 K-steps
    #pragma unroll
    for (int nt = 0; nt < 4; nt++) {
        const int row = s0 + w * 64 + nt * 16 + n;
        const f16* src = h0b + ((size_t)b * TMAX + row) * (2*H) + q * 8;
        #pragma unroll
        for (int kc = 0; kc < 4; kc++)
            bfr[nt][kc] = *(const f16x8*)(src + kc * 32);
    }
    f16* Gb = G + (size_t)b * CH * 256;
    for (int mt = 0; mt < 16; mt++) {
        f16x8 afr[4];
        #pragma unroll
        for (int kc = 0; kc < 4; kc++)
            afr[kc] = *(const f16x8*)(Wi + (size_t)(mt*16 + n) * 128 + kc*32 + q*8);
        #pragma unroll
        for (int nt = 0; nt < 4; nt++) {
            f32x4 acc = {0.f, 0.f, 0.f, 0.f};
            #pragma unroll
            for (int kc = 0; kc < 4; kc++)
                acc = MFMA16(afr[kc], bfr[nt][kc], acc);
            // D[m=q*4+reg][n] -> row r, cols R=mt*16+q*4+reg (interleaved)
            f16x4 o;
            o[0] = (f16)acc[0]; o[1] = (f16)acc[1];
            o[2] = (f16)acc[2]; o[3] = (f16)acc[3];
            const int r = w * 64 + nt * 16 + n;
            *(f16x4*)(Gb + (size_t)r * 256 + mt*16 + q*4) = o;
        }
    }
}

// ======== Layer 1 recurrence: ONE WAVE per seq, zero barriers ===============
// Same structure as lstm0_sw; xW comes from G (one coalesced 8B load/lane/
// step, 3-deep register prefetch). State carried across the 4 chunk launches.
__global__ __launch_bounds__(64) void rec_sw(
    const f16* __restrict__ G, const int* __restrict__ lengths,
    const float* __restrict__ Whh,
    const float* __restrict__ bih, const float* __restrict__ bhh,
    float* __restrict__ cst, float* __restrict__ hst,
    float* __restrict__ ylast, int s0)
{
    const int b = blockIdx.x, j = threadIdx.x;
    const int L = lengths[b];
    if (L <= s0) return;
    const int send = min(L, s0 + CH);

    h2 whh2[4][32];
    float bs[4];
    #pragma unroll
    for (int r = 0; r < 4; r++) {
        const float4* p = (const float4*)(Whh + (size_t)(r*H + j) * H);
        #pragma unroll
        for (int k = 0; k < 16; k++) {
            float4 v = p[k];
            h2 lo; lo[0] = (f16)v.x; lo[1] = (f16)v.y;
            h2 hi; hi[0] = (f16)v.z; hi[1] = (f16)v.w;
            whh2[r][2*k] = lo; whh2[r][2*k + 1] = hi;
        }
        bs[r] = bih[r*H + j] + bhh[r*H + j];
    }
    __shared__ __align__(16) f16 hbuf[H];
    float c, h;
    if (s0 == 0) { c = 0.f; h = 0.f; }
    else { c = cst[(size_t)b*H + j]; h = hst[(size_t)b*H + j]; }
    hbuf[j] = (f16)h;

    const f16* Gb = G + (size_t)b * CH * 256 + 4 * j;
    auto gld = [&](int r) -> f16x4 {        // coalesced 512B/wave
        r = min(r, CH - 1);
        return *(const f16x4*)(Gb + (size_t)r * 256);
    };
    f16x4 g0 = gld(0), g1 = gld(1), g2 = gld(2);

    for (int s = s0; s < send; s++) {
        f16x8 hr[8];
        const f16x8* hp = (const f16x8*)hbuf;
        #pragma unroll
        for (int k = 0; k < 8; k++) hr[k] = hp[k];

        float a0 = bs[0] + (float)g0[0];
        float a1 = bs[1] + (float)g0[1];
        float a2 = bs[2] + (float)g0[2];
        float a3 = bs[3] + (float)g0[3];
        #pragma unroll
        for (int k = 0; k < 8; k++) {
            #pragma unroll
            for (int i = 0; i < 4; i++) {
                const h2 hh = hpair(hr[k], i);
                const int p = 4*k + i;
                a0 = dot2(whh2[0][p], hh, a0);
                a1 = dot2(whh2[1][p], hh, a1);
                a2 = dot2(whh2[2][p], hh, a2);
                a3 = dot2(whh2[3][p], hh, a3);
            }
        }
        const float gi = sigmoidf_(a0), gf = sigmoidf_(a1);
        const float gg = tanhf_(a2),  go = sigmoidf_(a3);
        c = fmaf(gf, c, gi * gg);
        h = go * tanhf_(c);
        if (s == L - 1) ylast[(size_t)b * H + j] = h;  // wave-uniform cond
        hbuf[j] = (f16)h;
        g0 = g1; g1 = g2; g2 = gld(s + 3 - s0);
    }
    if (send < L) {
        cst[(size_t)b*H + j] = c;
        hst[(size_t)b*H + j] = h;
    }
}

// ====== Epilogue: bwd first step (zero state -> Whh_l1b unused) + logits ====
__global__ __launch_bounds__(256) void epi_kernel(
    const f16* __restrict__ h0b, const float* __restrict__ ylast,
    const int* __restrict__ lengths,
    const float* __restrict__ Wih_b,
    const float* __restrict__ bih_b, const float* __restrict__ bhh_b,
    const float* __restrict__ Wout, const float* __restrict__ bout,
    float* __restrict__ out)
{
    const int b = blockIdx.x;
    const int t = threadIdx.x;
    const int L = lengths[b];
    __shared__ __align__(16) float y[2*H];
    __shared__ __align__(16) float xrow[2*H];
    __shared__ float gb[256];

    if (t < 2*H) xrow[t] = (float)h0b[((size_t)b * TMAX + (L - 1)) * (2*H) + t];
    if (t < H)   y[t] = ylast[(size_t)b * H + t];
    __syncthreads();
    {
        float a0 = bih_b[t] + bhh_b[t], a1 = 0.f, a2 = 0.f, a3 = 0.f;
        const float4* wr = (const float4*)(Wih_b + (size_t)t * (2*H));
        const float4* xv = (const float4*)xrow;
        #pragma unroll
        for (int k = 0; k < 32; k++) {
            float4 wv = wr[k], xk = xv[k];
            a0 = fmaf(wv.x, xk.x, a0); a1 = fmaf(wv.y, xk.y, a1);
            a2 = fmaf(wv.z, xk.z, a2); a3 = fmaf(wv.w, xk.w, a3);
        }
        const float a = (a0 + a1) + (a2 + a3);
        gb[t] = (t >= 128 && t < 192) ? tanhf_(a) : sigmoidf_(a);
    }
    __syncthreads();
    if (t < H) {
        const float cb = gb[t] * gb[128 + t];       // c_prev = 0, f unused
        y[H + t] = gb[192 + t] * tanhf_(cb);
    }
    __syncthreads();

    const float4* yv = (const float4*)y;
    for (int o = t; o < NC; o += 256) {
        float a0 = bout[o], a1 = 0.f, a2 = 0.f, a3 = 0.f;
        const float4* wr = (const float4*)(Wout + (size_t)o * (2*H));
        #pragma unroll
        for (int k = 0; k < 32; k++) {
            float4 wv = wr[k], yy = yv[k];
            a0 = fmaf(wv.x, yy.x, a0); a1 = fmaf(wv.y, yy.y, a1);
            a2 = fmaf(wv.z, yy.z, a2); a3 = fmaf(wv.w, yy.w, a3);
        }
        out[(size_t)b * NC + o] = (a0 + a1) + (a2 + a3);
    }
}

extern "C" void kernel_launch(void* const* d_in, const int* in_sizes, int n_in,
                              void* d_out, int out_size, void* d_ws, size_t ws_size,
                              hipStream_t stream) {
    const float* x        = (const float*)d_in[0];
    const int*   lengths  = (const int*)  d_in[1];
    const float* Wih_l0f  = (const float*)d_in[2];
    const float* Whh_l0f  = (const float*)d_in[3];
    const float* bih_l0f  = (const float*)d_in[4];
    const float* bhh_l0f  = (const float*)d_in[5];
    const float* Wih_l0b  = (const float*)d_in[6];
    const float* Whh_l0b  = (const float*)d_in[7];
    const float* bih_l0b  = (const float*)d_in[8];
    const float* bhh_l0b  = (const float*)d_in[9];
    const float* Wih_l1f  = (const float*)d_in[10];
    const float* Whh_l1f  = (const float*)d_in[11];
    const float* bih_l1f  = (const float*)d_in[12];
    const float* bhh_l1f  = (const float*)d_in[13];
    const float* Wih_l1b  = (const float*)d_in[14];
    // d_in[15] = Whh_l1b: unused (backward dir only needs its first step, h=0)
    const float* bih_l1b  = (const float*)d_in[16];
    const float* bhh_l1b  = (const float*)d_in[17];
    const float* Wout     = (const float*)d_in[18];
    const float* bout     = (const float*)d_in[19];
    float* out = (float*)d_out;

    // ws (<= 202 MB, proven >= 256 MiB):
    //   h0 f16 [B,T,2H] 128 MiB | Wi f16 [256,128] 64 KiB |
    //   G f16 [B,CH,256] 64 MiB | cst/hst/ylast f32 [B,64] x3
    f16* h0b = (f16*)d_ws;
    f16* Wi  = h0b + (size_t)BATCH * TMAX * (2*H);
    f16* G   = Wi + 256 * 128;
    float* cst   = (float*)(G + (size_t)BATCH * CH * 256);
    float* hst   = cst + BATCH * H;
    float* ylast = hst + BATCH * H;

    prep_w<<<dim3(128), 256, 0, stream>>>(Wih_l1f, Wi);

    lstm0_sw<<<dim3(2 * BATCH), 64, 0, stream>>>(
        x, lengths,
        Wih_l0f, Whh_l0f, bih_l0f, bhh_l0f,
        Wih_l0b, Whh_l0b, bih_l0b, bhh_l0b, h0b);

    for (int k = 0; k < 4; k++) {
        xw_gemm<<<dim3(BATCH), 256, 0, stream>>>(h0b, Wi, lengths, G, k * CH);
        rec_sw<<<dim3(BATCH), 64, 0, stream>>>(
            G, lengths, Whh_l1f, bih_l1f, bhh_l1f, cst, hst, ylast, k * CH);
    }

    epi_kernel<<<dim3(BATCH), 256, 0, stream>>>(
        h0b, ylast, lengths,
        Wih_l1b, bih_l1b, bhh_l1b, Wout, bout, out);
}